// Round 4
// baseline (33.325 us; speedup 1.0000x reference)
//
#include <hip/hip_runtime.h>

// Problem constants (fixed by the reference)
#define N_ROWS 4096
#define D_DIM  1024
#define NCLS   10

// loss = ( ||s||_F^2 + ||t||_F^2 - 2 * sum_c S_c . T_c / n_c ) / N
// where S_c, T_c are per-class column sums of fm_s / fm_t.

#define CHUNK     32
#define NCHUNK    (N_ROWS / CHUNK)          // 128
#define K1_BLOCKS 256                       // 2 mats x 128 chunks
#define K2_BLOCKS 160                       // 10 cls x 16 col-slices (64 cols)
#define PART_FLOATS (NCHUNK * NCLS * D_DIM) // 1,310,720 per matrix

// ws float-offsets
#define OFF_CTR   0                          // 1 int (k2 ticket; k1 resets it)
#define OFF_ACC2  16                         // up to 512 floats (block sum-of-squares)
#define OFF_DOTP  528                        // 160 floats (per-(cls,slice) dots)
#define OFF_PART  688                        // 16B-aligned (688*4 % 16 == 0)
#define NEED_FLOATS (OFF_PART + 2 * PART_FLOATS)   // ~10.5 MB

// fallback (atomic) layout — only if ws is tiny (not expected: ws = 256 MiB)
#define FB_SLICE_W 512
#define FB_OFF_SUM 688                       // 2*10*1024 class sums
#define FB_NEED    (FB_OFF_SUM + 2 * NCLS * D_DIM)

// ---------------------------------------------------------------------------
// k1: one streaming pass over both matrices. Block = (mat, 32-row chunk),
// full 1024-col rows via float4 (256 thr * 4). 16-deep load batches.
// Class accumulation via wave-uniform scalar switch (4 VALU adds / float4).
__global__ __launch_bounds__(256) void k_pass1(const float* __restrict__ fm_s,
                                               const float* __restrict__ fm_t,
                                               const int* __restrict__ tgt,
                                               float* __restrict__ ws) {
    const int bid = blockIdx.x, tid = threadIdx.x;
    const int mat   = bid >> 7;          // 0 = s, 1 = t
    const int chunk = bid & 127;

    if (bid == 0 && tid == 0) ((int*)ws)[OFF_CTR] = 0;   // reset k2 ticket

    __shared__ int tl[CHUNK];
    if (tid < CHUNK) tl[tid] = tgt[chunk * CHUNK + tid];
    __syncthreads();

    const float* src  = mat ? fm_t : fm_s;
    const float* base = src + (size_t)chunk * CHUNK * D_DIM + tid * 4;

    float4 a[NCLS];
#pragma unroll
    for (int k = 0; k < NCLS; ++k) a[k] = make_float4(0.f, 0.f, 0.f, 0.f);
    float acc2 = 0.f;

#pragma unroll
    for (int r0 = 0; r0 < CHUNK; r0 += 16) {
        float4 v[16];
#pragma unroll
        for (int j = 0; j < 16; ++j)
            v[j] = *(const float4*)(base + (size_t)(r0 + j) * D_DIM);
#pragma unroll
        for (int j = 0; j < 16; ++j) {
            const float4 w = v[j];
            acc2 += w.x * w.x + w.y * w.y + w.z * w.z + w.w * w.w;
            const int c = __builtin_amdgcn_readfirstlane(tl[r0 + j]);  // wave-uniform
            switch (c) {
                case 0: a[0].x += w.x; a[0].y += w.y; a[0].z += w.z; a[0].w += w.w; break;
                case 1: a[1].x += w.x; a[1].y += w.y; a[1].z += w.z; a[1].w += w.w; break;
                case 2: a[2].x += w.x; a[2].y += w.y; a[2].z += w.z; a[2].w += w.w; break;
                case 3: a[3].x += w.x; a[3].y += w.y; a[3].z += w.z; a[3].w += w.w; break;
                case 4: a[4].x += w.x; a[4].y += w.y; a[4].z += w.z; a[4].w += w.w; break;
                case 5: a[5].x += w.x; a[5].y += w.y; a[5].z += w.z; a[5].w += w.w; break;
                case 6: a[6].x += w.x; a[6].y += w.y; a[6].z += w.z; a[6].w += w.w; break;
                case 7: a[7].x += w.x; a[7].y += w.y; a[7].z += w.z; a[7].w += w.w; break;
                case 8: a[8].x += w.x; a[8].y += w.y; a[8].z += w.z; a[8].w += w.w; break;
                default: a[9].x += w.x; a[9].y += w.y; a[9].z += w.z; a[9].w += w.w; break;
            }
        }
    }

    // partials layout: [mat][chunk][cls][col]
    float* part = ws + OFF_PART + (size_t)mat * PART_FLOATS
                + (size_t)chunk * (NCLS * D_DIM) + tid * 4;
#pragma unroll
    for (int k = 0; k < NCLS; ++k)
        *(float4*)(part + (size_t)k * D_DIM) = a[k];

    __shared__ float red[256];
    red[tid] = acc2;
    __syncthreads();
    for (int s = 128; s > 0; s >>= 1) {
        if (tid < s) red[tid] += red[tid + s];
        __syncthreads();
    }
    if (tid == 0) ws[OFF_ACC2 + bid] = red[0];
}

// ---------------------------------------------------------------------------
// k2: block b = (cls = b>>4, 64-col slice = b&15). Threads (grp=tid>>4 over
// chunk-groups, pos=tid&15 over float4 cols). Reduce 128 chunks for S and T,
// dot, write dotp[b]. Last ticket block: histogram (register-count + LDS
// tree, no atomics in the hot path) + final double reduce.
__global__ __launch_bounds__(256) void k_pass2(const int* __restrict__ tgt,
                                               float* __restrict__ ws,
                                               float* __restrict__ out) {
    const int b = blockIdx.x, tid = threadIdx.x;
    const int cls  = b >> 4;
    const int bcol = (b & 15) * 64;
    const int grp  = tid >> 4;           // 0..15: chunk group (8 chunks each)
    const int pos  = tid & 15;           // 0..15: float4 col within slice

    const size_t cstride = NCLS * D_DIM;   // chunk stride in partials
    const float* baseS = ws + OFF_PART + (size_t)(grp * 8) * cstride
                       + (size_t)cls * D_DIM + bcol + pos * 4;
    const float* baseT = baseS + PART_FLOATS;

    float4 aS = make_float4(0, 0, 0, 0), aT = make_float4(0, 0, 0, 0);
#pragma unroll
    for (int j = 0; j < 8; ++j) {
        float4 vS = *(const float4*)(baseS + (size_t)j * cstride);
        float4 vT = *(const float4*)(baseT + (size_t)j * cstride);
        aS.x += vS.x; aS.y += vS.y; aS.z += vS.z; aS.w += vS.w;
        aT.x += vT.x; aT.y += vT.y; aT.z += vT.z; aT.w += vT.w;
    }

    __shared__ float4 sS[16][16], sT[16][16];
    sS[grp][pos] = aS;
    sT[grp][pos] = aT;
    __syncthreads();
    for (int h = 8; h > 0; h >>= 1) {
        if (grp < h) {
            float4 x = sS[grp + h][pos], y = sS[grp][pos];
            y.x += x.x; y.y += x.y; y.z += x.z; y.w += x.w;
            sS[grp][pos] = y;
            x = sT[grp + h][pos]; y = sT[grp][pos];
            y.x += x.x; y.y += x.y; y.z += x.z; y.w += x.w;
            sT[grp][pos] = y;
        }
        __syncthreads();
    }

    __shared__ float dred[16];
    if (tid < 16) {
        float4 S = sS[0][tid], T = sT[0][tid];
        dred[tid] = S.x * T.x + S.y * T.y + S.z * T.z + S.w * T.w;
    }
    __syncthreads();
    if (tid < 8) dred[tid] += dred[tid + 8];
    __syncthreads();
    if (tid < 4) dred[tid] += dred[tid + 4];
    __syncthreads();

    // last-block ticket (device-scope fences: G16 XCD non-coherence)
    __shared__ int isLast;
    if (tid == 0) {
        ws[OFF_DOTP + b] = (dred[0] + dred[1]) + (dred[2] + dred[3]);
        __threadfence();
        int old = atomicAdd((int*)ws + OFF_CTR, 1);
        isLast = (old == K2_BLOCKS - 1) ? 1 : 0;
    }
    __syncthreads();
    if (!isLast) return;
    __threadfence();

    // histogram: register counting, LDS combine (no atomics)
    int cnt[NCLS];
#pragma unroll
    for (int k = 0; k < NCLS; ++k) cnt[k] = 0;
#pragma unroll
    for (int j = 0; j < 16; ++j) {
        int c = tgt[tid * 16 + j];
#pragma unroll
        for (int k = 0; k < NCLS; ++k) cnt[k] += (c == k) ? 1 : 0;
    }
    __shared__ int hl[256 * NCLS];
#pragma unroll
    for (int k = 0; k < NCLS; ++k) hl[tid * NCLS + k] = cnt[k];
    __syncthreads();
    __shared__ int hist[NCLS];
    if (tid < NCLS) {
        int s = 0;
        for (int i = 0; i < 256; ++i) s += hl[i * NCLS + tid];
        hist[tid] = s;
    }
    __syncthreads();

    double v = (double)ws[OFF_ACC2 + tid];          // 256 k1 blocks
    if (tid < K2_BLOCKS) {
        int n = hist[tid >> 4];
        if (n > 0) v -= 2.0 * (double)ws[OFF_DOTP + tid] / (double)n;
    }
    __shared__ double fr[256];
    fr[tid] = v;
    __syncthreads();
    for (int s = 128; s > 0; s >>= 1) {
        if (tid < s) fr[tid] += fr[tid + s];
        __syncthreads();
    }
    if (tid == 0) out[0] = (float)(fr[0] / (double)N_ROWS);
}

// ------------------------- atomic fallback (tiny ws; never expected) --------
__global__ void k_fb_zero(float* __restrict__ ws) {
    int i = blockIdx.x * 256 + threadIdx.x;
    if (i < 2 * NCLS * D_DIM) ws[FB_OFF_SUM + i] = 0.f;
}

__global__ __launch_bounds__(256) void k_fb_acc(const float* __restrict__ fm_s,
                                                const float* __restrict__ fm_t,
                                                const int* __restrict__ tgt,
                                                float* __restrict__ ws) {
    const int bid = blockIdx.x, tid = threadIdx.x;   // 512 blocks
    const int mat   = bid >> 8;
    const int rem   = bid & 255;
    const int slice = rem >> 7;
    const int chunk = rem & 127;

    __shared__ int tl[CHUNK];
    if (tid < CHUNK) tl[tid] = tgt[chunk * CHUNK + tid];
    __syncthreads();

    const float* src  = mat ? fm_t : fm_s;
    const float* base = src + (size_t)chunk * CHUNK * D_DIM + slice * FB_SLICE_W + tid * 2;

    float2 a[NCLS];
#pragma unroll
    for (int k = 0; k < NCLS; ++k) a[k] = make_float2(0.f, 0.f);
    float acc2 = 0.f;

    for (int r = 0; r < CHUNK; ++r) {
        float2 v = *(const float2*)(base + (size_t)r * D_DIM);
        acc2 += v.x * v.x + v.y * v.y;
        const int c = __builtin_amdgcn_readfirstlane(tl[r]);
        switch (c) {
            case 0: a[0].x += v.x; a[0].y += v.y; break;
            case 1: a[1].x += v.x; a[1].y += v.y; break;
            case 2: a[2].x += v.x; a[2].y += v.y; break;
            case 3: a[3].x += v.x; a[3].y += v.y; break;
            case 4: a[4].x += v.x; a[4].y += v.y; break;
            case 5: a[5].x += v.x; a[5].y += v.y; break;
            case 6: a[6].x += v.x; a[6].y += v.y; break;
            case 7: a[7].x += v.x; a[7].y += v.y; break;
            case 8: a[8].x += v.x; a[8].y += v.y; break;
            default: a[9].x += v.x; a[9].y += v.y; break;
        }
    }

    int col = slice * FB_SLICE_W + tid * 2;
    float* dst = ws + FB_OFF_SUM + (size_t)mat * NCLS * D_DIM + col;
#pragma unroll
    for (int k = 0; k < NCLS; ++k) {
        atomicAdd(dst + (size_t)k * D_DIM,     a[k].x);
        atomicAdd(dst + (size_t)k * D_DIM + 1, a[k].y);
    }

    __shared__ float red[256];
    red[tid] = acc2;
    __syncthreads();
    for (int s = 128; s > 0; s >>= 1) {
        if (tid < s) red[tid] += red[tid + s];
        __syncthreads();
    }
    if (tid == 0) ws[OFF_ACC2 + bid] = red[0];
}

__global__ __launch_bounds__(256) void k_fb_fin(const int* __restrict__ tgt,
                                                float* __restrict__ ws,
                                                float* __restrict__ out) {
    const int tid = threadIdx.x;
    __shared__ int hist[NCLS];
    if (tid < NCLS) hist[tid] = 0;
    __syncthreads();
    for (int i = tid; i < N_ROWS; i += 256) atomicAdd(&hist[tgt[i]], 1);
    __syncthreads();

    double v = (double)ws[OFF_ACC2 + tid] + (double)ws[OFF_ACC2 + tid + 256];
    for (int i = tid; i < NCLS * D_DIM; i += 256) {
        int n = hist[i >> 10];
        if (n > 0) {
            double sS = ws[FB_OFF_SUM + i];
            double sT = ws[FB_OFF_SUM + NCLS * D_DIM + i];
            v -= 2.0 * sS * sT / (double)n;
        }
    }
    __shared__ double dred[256];
    dred[tid] = v;
    __syncthreads();
    for (int s = 128; s > 0; s >>= 1) {
        if (tid < s) dred[tid] += dred[tid + s];
        __syncthreads();
    }
    if (tid == 0) out[0] = (float)(dred[0] / (double)N_ROWS);
}

// ---------------------------------------------------------------------------
extern "C" void kernel_launch(void* const* d_in, const int* in_sizes, int n_in,
                              void* d_out, int out_size, void* d_ws, size_t ws_size,
                              hipStream_t stream) {
    const float* fm_s = (const float*)d_in[0];
    const float* fm_t = (const float*)d_in[1];
    const int*   tgt  = (const int*)d_in[2];
    // d_in[3] (fusion_true) unused: reference takes the fusion_true==0 branch.

    float* ws   = (float*)d_ws;
    float* outp = (float*)d_out;

    if (ws_size >= (size_t)NEED_FLOATS * sizeof(float)) {
        k_pass1<<<K1_BLOCKS, 256, 0, stream>>>(fm_s, fm_t, tgt, ws);
        k_pass2<<<K2_BLOCKS, 256, 0, stream>>>(tgt, ws, outp);
    } else {
        k_fb_zero<<<(2 * NCLS * D_DIM + 255) / 256, 256, 0, stream>>>(ws);
        k_fb_acc<<<512, 256, 0, stream>>>(fm_s, fm_t, tgt, ws);
        k_fb_fin<<<1, 256, 0, stream>>>(tgt, ws, outp);
    }
}

// Round 5
// 30.447 us; speedup vs baseline: 1.0945x; 1.0945x over previous
//
#include <hip/hip_runtime.h>

// Problem constants (fixed by the reference)
#define N_ROWS 4096
#define D_DIM  1024
#define NCLS   10

// loss = ( ||s||_F^2 + ||t||_F^2 - 2 * sum_c S_c . T_c / n_c ) / N
// where S_c, T_c are per-class column sums of fm_s / fm_t.

#define ROWS_PB   64
#define NCHUNK    (N_ROWS / ROWS_PB)        // 64
#define SLICE_W   256
#define NSLICE    (D_DIM / SLICE_W)         // 4
#define K1_BLOCKS (2 * NCHUNK * NSLICE)     // 512 -> 2 blocks/CU, 8 waves/CU
#define K2_COLG   32                        // 32-col groups
#define K2_BLOCKS (NCLS * K2_COLG)          // 320

#define CHUNKCOL  (NCHUNK * SLICE_W)        // 16384
#define PART_PER_MAT (NSLICE * NCLS * CHUNKCOL)   // 655,360 floats (2.6 MB)
// partial layout: [mat][slice][cls][chunk][col256]

// ws float-offsets (nothing needs pre-zeroing; k1 resets the k2 ticket)
#define OFF_CTR   0                          // 1 int
#define OFF_ACC2  16                         // 512 floats (k1 block sum-of-squares)
#define OFF_DOTP  528                        // 320 floats
#define OFF_PART  848                        // 848*4 % 16 == 0
#define NEED_FLOATS (OFF_PART + 2 * PART_PER_MAT)   // ~5.2 MB

// fallback (atomic) layout — only if ws is tiny (not expected: ws = 256 MiB)
#define FB_SLICE_W 512
#define FB_OFF_SUM 848
#define FB_NEED    (FB_OFF_SUM + 2 * NCLS * D_DIM)

// ---------------------------------------------------------------------------
// k1: one streaming pass over both matrices.
// Block = (mat, 64-row chunk, 256-col slice); 512 blocks, 256 threads.
// Per-thread class accumulators live in an LDS stripe of 11 floats
// (stride 11 is coprime with 32 banks -> conflict-free; 2 parity copies
// break the read-modify-write dependency chain). Classes are read via
// wave-uniform addresses -> scalar loads, no DS traffic, no branches.
__global__ __launch_bounds__(256) void k_pass1(const float* __restrict__ fm_s,
                                               const float* __restrict__ fm_t,
                                               const int* __restrict__ tgt,
                                               float* __restrict__ ws) {
    const int bid = blockIdx.x, tid = threadIdx.x;
    const int mat   = bid >> 8;          // 0 = s, 1 = t
    const int rem   = bid & 255;
    const int chunk = rem >> 2;          // 0..63
    const int slice = rem & 3;           // 0..3

    if (bid == 0 && tid == 0) ((int*)ws)[OFF_CTR] = 0;   // reset k2 ticket

    // 2 parity copies * 256 threads * 11-float stripe
    __shared__ float acc[2 * 256 * 11];
#pragma unroll
    for (int k = 0; k < 11; ++k) {
        acc[tid * 11 + k]        = 0.f;
        acc[2816 + tid * 11 + k] = 0.f;
    }
    // no __syncthreads needed: each thread touches only its own stripes

    const int*   tgc  = tgt + chunk * ROWS_PB;   // wave-uniform base -> s_load
    const float* src  = mat ? fm_t : fm_s;
    const float* base = src + (size_t)chunk * ROWS_PB * D_DIM + slice * SLICE_W + tid;

    float acc2 = 0.f;
#pragma unroll
    for (int r0 = 0; r0 < ROWS_PB; r0 += 16) {
        float v[16];
#pragma unroll
        for (int j = 0; j < 16; ++j)
            v[j] = base[(size_t)(r0 + j) * D_DIM];
#pragma unroll
        for (int j = 0; j < 16; ++j) {
            const int   c = tgc[r0 + j];         // uniform -> SGPR
            const float x = v[j];
            acc2 = fmaf(x, x, acc2);
            const int par = (j & 1) ? 2816 : 0;  // break RMW chain
            acc[par + tid * 11 + c] += x;
        }
    }

    // partials: [mat][slice][cls][chunk][col]
    float* pb = ws + OFF_PART + (size_t)mat * PART_PER_MAT
              + (size_t)slice * (NCLS * CHUNKCOL)
              + (size_t)chunk * SLICE_W + tid;
#pragma unroll
    for (int k = 0; k < NCLS; ++k)
        pb[(size_t)k * CHUNKCOL] = acc[tid * 11 + k] + acc[2816 + tid * 11 + k];

    __shared__ float red[256];
    red[tid] = acc2;
    __syncthreads();
    for (int s = 128; s > 0; s >>= 1) {
        if (tid < s) red[tid] += red[tid + s];
        __syncthreads();
    }
    if (tid == 0) ws[OFF_ACC2 + bid] = red[0];
}

// ---------------------------------------------------------------------------
// k2: block b = (cls = b>>5, 32-col group = b&31). 320 blocks, 16 KB each.
// Threads: sub = tid>>5 (8 chunk-subsets of 8), col = tid&31. Reduce over
// 64 chunks for S and T, dot, write dotp[b]. Last ticket block: histogram
// (register count + LDS combine, no hot atomics) + final double reduce.
__global__ __launch_bounds__(256) void k_pass2(const int* __restrict__ tgt,
                                               float* __restrict__ ws,
                                               float* __restrict__ out) {
    const int b = blockIdx.x, tid = threadIdx.x;
    const int cls   = b >> 5;
    const int grp   = b & 31;
    const int slice = grp >> 3;
    const int col0  = (grp & 7) * 32;
    const int sub   = tid >> 5;          // 0..7
    const int cl    = tid & 31;
    const int col   = col0 + cl;

    const float* pS = ws + OFF_PART
                    + (size_t)slice * (NCLS * CHUNKCOL)
                    + (size_t)cls * CHUNKCOL
                    + (size_t)(sub * 8) * SLICE_W + col;
    const float* pT = pS + PART_PER_MAT;

    float aS = 0.f, aT = 0.f;
#pragma unroll
    for (int j = 0; j < 8; ++j) {
        aS += pS[(size_t)j * SLICE_W];
        aT += pT[(size_t)j * SLICE_W];
    }

    __shared__ float sS[8][32], sT[8][32];
    sS[sub][cl] = aS;
    sT[sub][cl] = aT;
    __syncthreads();
    for (int h = 4; h > 0; h >>= 1) {
        if (sub < h) {
            sS[sub][cl] += sS[sub + h][cl];
            sT[sub][cl] += sT[sub + h][cl];
        }
        __syncthreads();
    }

    __shared__ float pr[32];
    if (tid < 32) pr[tid] = sS[0][tid] * sT[0][tid];
    __syncthreads();
    for (int h = 16; h > 0; h >>= 1) {
        if (tid < h) pr[tid] += pr[tid + h];
        __syncthreads();
    }

    // last-block ticket (device-scope fences: G16 XCD non-coherence)
    __shared__ int isLast;
    if (tid == 0) {
        ws[OFF_DOTP + b] = pr[0];
        __threadfence();
        int old = atomicAdd((int*)ws + OFF_CTR, 1);
        isLast = (old == K2_BLOCKS - 1) ? 1 : 0;
    }
    __syncthreads();
    if (!isLast) return;
    __threadfence();

    // histogram: register counting, LDS combine
    int cnt[NCLS];
#pragma unroll
    for (int k = 0; k < NCLS; ++k) cnt[k] = 0;
#pragma unroll
    for (int j = 0; j < 16; ++j) {
        int c = tgt[tid * 16 + j];
#pragma unroll
        for (int k = 0; k < NCLS; ++k) cnt[k] += (c == k) ? 1 : 0;
    }
    __shared__ int hl[256 * NCLS];
#pragma unroll
    for (int k = 0; k < NCLS; ++k) hl[tid * NCLS + k] = cnt[k];
    __syncthreads();
    __shared__ int hist[NCLS];
    if (tid < NCLS) {
        int s = 0;
        for (int i = 0; i < 256; ++i) s += hl[i * NCLS + tid];
        hist[tid] = s;
    }
    __syncthreads();

    double v = (double)ws[OFF_ACC2 + tid] + (double)ws[OFF_ACC2 + tid + 256];
    if (tid < K2_BLOCKS) {
        int n = hist[tid >> 5];
        if (n > 0) v -= 2.0 * (double)ws[OFF_DOTP + tid] / (double)n;
    }
    __shared__ double fr[256];
    fr[tid] = v;
    __syncthreads();
    for (int s = 128; s > 0; s >>= 1) {
        if (tid < s) fr[tid] += fr[tid + s];
        __syncthreads();
    }
    if (tid == 0) out[0] = (float)(fr[0] / (double)N_ROWS);
}

// ------------------------- atomic fallback (tiny ws; never expected) --------
__global__ void k_fb_zero(float* __restrict__ ws) {
    int i = blockIdx.x * 256 + threadIdx.x;
    if (i < 2 * NCLS * D_DIM) ws[FB_OFF_SUM + i] = 0.f;
}

__global__ __launch_bounds__(256) void k_fb_acc(const float* __restrict__ fm_s,
                                                const float* __restrict__ fm_t,
                                                const int* __restrict__ tgt,
                                                float* __restrict__ ws) {
    const int bid = blockIdx.x, tid = threadIdx.x;   // 512 blocks
    const int mat   = bid >> 8;
    const int rem   = bid & 255;
    const int slice = rem >> 7;
    const int chunk = rem & 127;

    __shared__ int tl[32];
    if (tid < 32) tl[tid] = tgt[chunk * 32 + tid];
    __syncthreads();

    const float* src  = mat ? fm_t : fm_s;
    const float* base = src + (size_t)chunk * 32 * D_DIM + slice * FB_SLICE_W + tid * 2;

    float2 a[NCLS];
#pragma unroll
    for (int k = 0; k < NCLS; ++k) a[k] = make_float2(0.f, 0.f);
    float acc2 = 0.f;

    for (int r = 0; r < 32; ++r) {
        float2 v = *(const float2*)(base + (size_t)r * D_DIM);
        acc2 += v.x * v.x + v.y * v.y;
        const int c = __builtin_amdgcn_readfirstlane(tl[r]);
        switch (c) {
            case 0: a[0].x += v.x; a[0].y += v.y; break;
            case 1: a[1].x += v.x; a[1].y += v.y; break;
            case 2: a[2].x += v.x; a[2].y += v.y; break;
            case 3: a[3].x += v.x; a[3].y += v.y; break;
            case 4: a[4].x += v.x; a[4].y += v.y; break;
            case 5: a[5].x += v.x; a[5].y += v.y; break;
            case 6: a[6].x += v.x; a[6].y += v.y; break;
            case 7: a[7].x += v.x; a[7].y += v.y; break;
            case 8: a[8].x += v.x; a[8].y += v.y; break;
            default: a[9].x += v.x; a[9].y += v.y; break;
        }
    }

    int col = slice * FB_SLICE_W + tid * 2;
    float* dst = ws + FB_OFF_SUM + (size_t)mat * NCLS * D_DIM + col;
#pragma unroll
    for (int k = 0; k < NCLS; ++k) {
        atomicAdd(dst + (size_t)k * D_DIM,     a[k].x);
        atomicAdd(dst + (size_t)k * D_DIM + 1, a[k].y);
    }

    __shared__ float red[256];
    red[tid] = acc2;
    __syncthreads();
    for (int s = 128; s > 0; s >>= 1) {
        if (tid < s) red[tid] += red[tid + s];
        __syncthreads();
    }
    if (tid == 0) ws[OFF_ACC2 + bid] = red[0];
}

__global__ __launch_bounds__(256) void k_fb_fin(const int* __restrict__ tgt,
                                                float* __restrict__ ws,
                                                float* __restrict__ out) {
    const int tid = threadIdx.x;
    __shared__ int hist[NCLS];
    if (tid < NCLS) hist[tid] = 0;
    __syncthreads();
    for (int i = tid; i < N_ROWS; i += 256) atomicAdd(&hist[tgt[i]], 1);
    __syncthreads();

    double v = (double)ws[OFF_ACC2 + tid] + (double)ws[OFF_ACC2 + tid + 256];
    for (int i = tid; i < NCLS * D_DIM; i += 256) {
        int n = hist[i >> 10];
        if (n > 0) {
            double sS = ws[FB_OFF_SUM + i];
            double sT = ws[FB_OFF_SUM + NCLS * D_DIM + i];
            v -= 2.0 * sS * sT / (double)n;
        }
    }
    __shared__ double dred[256];
    dred[tid] = v;
    __syncthreads();
    for (int s = 128; s > 0; s >>= 1) {
        if (tid < s) dred[tid] += dred[tid + s];
        __syncthreads();
    }
    if (tid == 0) out[0] = (float)(dred[0] / (double)N_ROWS);
}

// ---------------------------------------------------------------------------
extern "C" void kernel_launch(void* const* d_in, const int* in_sizes, int n_in,
                              void* d_out, int out_size, void* d_ws, size_t ws_size,
                              hipStream_t stream) {
    const float* fm_s = (const float*)d_in[0];
    const float* fm_t = (const float*)d_in[1];
    const int*   tgt  = (const int*)d_in[2];
    // d_in[3] (fusion_true) unused: reference takes the fusion_true==0 branch.

    float* ws   = (float*)d_ws;
    float* outp = (float*)d_out;

    if (ws_size >= (size_t)NEED_FLOATS * sizeof(float)) {
        k_pass1<<<K1_BLOCKS, 256, 0, stream>>>(fm_s, fm_t, tgt, ws);
        k_pass2<<<K2_BLOCKS, 256, 0, stream>>>(tgt, ws, outp);
    } else {
        k_fb_zero<<<(2 * NCLS * D_DIM + 255) / 256, 256, 0, stream>>>(ws);
        k_fb_acc<<<512, 256, 0, stream>>>(fm_s, fm_t, tgt, ws);
        k_fb_fin<<<1, 256, 0, stream>>>(tgt, ws, outp);
    }
}